// Round 2
// baseline (1602.640 us; speedup 1.0000x reference)
//
#include <hip/hip_runtime.h>

typedef __bf16 bf16;
typedef __bf16 bf16x8 __attribute__((ext_vector_type(8)));
typedef __bf16 bf16x4 __attribute__((ext_vector_type(4)));
typedef float f32x4 __attribute__((ext_vector_type(4)));

constexpr int kB = 64;
constexpr int kS = 2048;
constexpr int kD = 1024;          // decoder size (N of main GEMM)
constexpr int kM = 1024;          // memory size  (K of main GEMM)
constexpr int kRows = kB * kS;    // 131072

__device__ __forceinline__ float fast_tanh(float x) {
    float e = __expf(2.0f * x);
    return 1.0f - 2.0f * __builtin_amdgcn_rcpf(e + 1.0f);
}

// ---------------------------------------------------------------------------
// P1: WT[d][m] = bf16(W_mem[m][d])  — LDS-tiled coalesced transpose
__global__ __launch_bounds__(256) void wmem_transpose_kernel(
    const float* __restrict__ Wm, bf16* __restrict__ WT) {
    __shared__ float tile[64][65];
    const int tc = blockIdx.x;          // d-tile
    const int tr = blockIdx.y;          // m-tile
    const int lw = threadIdx.x >> 6;    // 0..3
    const int ll = threadIdx.x & 63;
    #pragma unroll
    for (int ii = 0; ii < 16; ++ii) {
        const int lr = ii * 4 + lw;
        tile[lr][ll] = Wm[(size_t)(tr * 64 + lr) * 1024 + tc * 64 + ll];
    }
    __syncthreads();
    #pragma unroll
    for (int ii = 0; ii < 16; ++ii) {
        const int ld = ii * 4 + lw;
        WT[(size_t)(tc * 64 + ld) * 1024 + tr * 64 + ll] = (bf16)tile[ll][ld];
    }
}

// ---------------------------------------------------------------------------
// P2: dec_feat[b][d] = sum_m dec[b][m] * W_dec[m][d]  (K-split for parallelism)
__global__ __launch_bounds__(256) void dec_project_kernel(
    const float* __restrict__ dec, const float* __restrict__ Wd,
    float* __restrict__ decf) {
    __shared__ float red[4][64];
    const int b  = blockIdx.x;
    const int dg = blockIdx.y;                 // 16 groups of 64 d
    const int d  = dg * 64 + (threadIdx.x & 63);
    const int mq = threadIdx.x >> 6;           // K quarter
    const float* drow = dec + b * kD;
    float acc = 0.f;
    #pragma unroll 8
    for (int m = mq * 256; m < (mq + 1) * 256; ++m)
        acc += drow[m] * Wd[(size_t)m * kD + d];
    red[mq][threadIdx.x & 63] = acc;
    __syncthreads();
    if (threadIdx.x < 64)
        decf[b * kD + dg * 64 + threadIdx.x] =
            red[0][threadIdx.x] + red[1][threadIdx.x] +
            red[2][threadIdx.x] + red[3][threadIdx.x];
}

// ---------------------------------------------------------------------------
// A: fused scores.  A (64 rows x full K=1024, bf16, XOR-swizzled) resident in
// LDS; B fragments read directly from L2-resident WT.  Block covers all 1024
// output cols -> memory_bank fetched exactly once.
__global__ __launch_bounds__(256, 1) void attn_scores_kernel(
    const float* __restrict__ MBank,   // [kRows, kM] fp32
    const bf16*  __restrict__ WT,      // [kD, kM]   bf16 (W_mem transposed)
    const float* __restrict__ decf,    // [kB, kD]
    const float* __restrict__ Wv,      // [kD]
    float* __restrict__ scores)        // [kRows]
{
    __shared__ __align__(16) bf16 Atile[64 * 1024];  // 128 KB, swizzled units
    __shared__ float sred[64 * 4];

    const int tid  = threadIdx.x;
    const int wave = tid >> 6;
    const int lane = tid & 63;
    const int ln   = lane & 15;
    const int quad = lane >> 4;

    const int bid   = blockIdx.x;      // 0..2047
    const int R0    = bid * 64;
    const int batch = bid >> 5;        // 32 blocks per batch row-range
    const float* Ab = MBank + (size_t)R0 * kM;

    f32x4 acc[2][4][8];
    #pragma unroll
    for (int c = 0; c < 2; ++c)
        #pragma unroll
        for (int i = 0; i < 4; ++i)
            #pragma unroll
            for (int j = 0; j < 8; ++j)
                acc[c][i][j] = (f32x4){0.f, 0.f, 0.f, 0.f};

    // ---- staging helpers: slice = 256-wide K range; half = 32-row half
    auto stageLoad = [&](int slice, int half, f32x4* v) {
        #pragma unroll
        for (int ii = 0; ii < 8; ++ii) {
            const int row = half * 32 + ii * 4 + wave;
            v[ii] = *(const f32x4*)(Ab + (size_t)row * kM + slice * 256 + lane * 4);
        }
    };
    auto stageWrite = [&](int slice, int half, const f32x4* v) {
        #pragma unroll
        for (int ii = 0; ii < 8; ++ii) {
            const int row = half * 32 + ii * 4 + wave;
            const int u = slice * 32 + (lane >> 1);        // 16B unit index
            bf16x4 w = {(bf16)v[ii][0], (bf16)v[ii][1],
                        (bf16)v[ii][2], (bf16)v[ii][3]};
            *(bf16x4*)(Atile + row * 1024 + ((u ^ (row & 7)) << 3) + (lane & 1) * 4) = w;
        }
    };
    auto bload = [&](int ct, int k0, bf16x8* bfr) {
        const bf16* bp = WT + (size_t)(ct * 512 + wave * 128 + ln) * 1024 + k0 + quad * 8;
        #pragma unroll
        for (int j = 0; j < 8; ++j)
            bfr[j] = *(const bf16x8*)(bp + (size_t)j * 16 * 1024);
    };
    auto step = [&](int ct, int k0, const bf16x8* bfr) {
        bf16x8 af[4];
        const int ku = k0 >> 3;
        #pragma unroll
        for (int i = 0; i < 4; ++i) {
            const int r = i * 16 + ln;
            af[i] = *(const bf16x8*)(Atile + r * 1024 + (((ku + quad) ^ (ln & 7)) << 3));
        }
        #pragma unroll
        for (int i = 0; i < 4; ++i)
            #pragma unroll
            for (int j = 0; j < 8; ++j)
                acc[ct][i][j] = __builtin_amdgcn_mfma_f32_16x16x32_bf16(
                    af[i], bfr[j], acc[ct][i][j], 0, 0, 0);
    };

    // ---- prologue: stage K-slice 0
    {
        f32x4 v[8];
        stageLoad(0, 0, v); stageWrite(0, 0, v);
        stageLoad(0, 1, v); stageWrite(0, 1, v);
    }

    bf16x8 bb[2][8];
    for (int kr = 0; kr < 4; ++kr) {
        __syncthreads();                         // slice kr now visible
        const int kbase = kr * 256;
        f32x4 v[8];
        if (kr < 3) stageLoad(kr + 1, 0, v);     // prefetch next slice, half 0
        bload(0, kbase, bb[0]);
        #pragma unroll
        for (int idx = 0; idx < 16; ++idx) {
            const int ct = idx >> 3;
            const int k0 = kbase + (idx & 7) * 32;
            if (idx == 8 && kr < 3) {            // mid-compute: commit half0, fetch half1
                stageWrite(kr + 1, 0, v);
                stageLoad(kr + 1, 1, v);
            }
            if (idx < 15)
                bload((idx + 1) >> 3, kbase + ((idx + 1) & 7) * 32, bb[(idx + 1) & 1]);
            step(ct, k0, bb[idx & 1]);
        }
        if (kr < 3) stageWrite(kr + 1, 1, v);
    }

    // ---- epilogue: tanh(E+decf)*Wv, reduce over all 1024 cols
    float wv[2][8], df[2][8];
    #pragma unroll
    for (int c = 0; c < 2; ++c)
        #pragma unroll
        for (int j = 0; j < 8; ++j) {
            const int col = c * 512 + wave * 128 + j * 16 + ln;
            wv[c][j] = Wv[col];
            df[c][j] = decf[batch * kD + col];
        }
    #pragma unroll
    for (int i = 0; i < 4; ++i) {
        #pragma unroll
        for (int r = 0; r < 4; ++r) {
            float p = 0.f;
            #pragma unroll
            for (int c = 0; c < 2; ++c)
                #pragma unroll
                for (int j = 0; j < 8; ++j)
                    p += fast_tanh(acc[c][i][j][r] + df[c][j]) * wv[c][j];
            #pragma unroll
            for (int off = 1; off < 16; off <<= 1)
                p += __shfl_xor(p, off, 64);     // sum over 16 cols (ln)
            if (ln == 0)
                sred[(i * 16 + quad * 4 + r) * 4 + wave] = p;
        }
    }
    __syncthreads();
    if (tid < 64)
        scores[R0 + tid] = sred[tid * 4] + sred[tid * 4 + 1] +
                           sred[tid * 4 + 2] + sred[tid * 4 + 3];
}

// ---------------------------------------------------------------------------
// B: softmax over S per batch
__global__ __launch_bounds__(256) void softmax_kernel(
    const float* __restrict__ scores, const int* __restrict__ mask,
    float* __restrict__ attn) {
    const int b = blockIdx.x;
    const int tid = threadIdx.x;
    __shared__ float sc[kS];
    __shared__ float redm[4], reds[4];

    float lmax = -INFINITY;
    for (int s = tid; s < kS; s += 256) {
        float v = scores[b * kS + s];
        if (mask[b * kS + s] == 0) v = -INFINITY;
        sc[s] = v;
        lmax = fmaxf(lmax, v);
    }
    #pragma unroll
    for (int off = 32; off; off >>= 1) lmax = fmaxf(lmax, __shfl_xor(lmax, off, 64));
    if ((tid & 63) == 0) redm[tid >> 6] = lmax;
    __syncthreads();
    const float bmax = fmaxf(fmaxf(redm[0], redm[1]), fmaxf(redm[2], redm[3]));

    float lsum = 0.f;
    for (int s = tid; s < kS; s += 256) {
        float e = __expf(sc[s] - bmax);
        sc[s] = e;
        lsum += e;
    }
    #pragma unroll
    for (int off = 32; off; off >>= 1) lsum += __shfl_xor(lsum, off, 64);
    if ((tid & 63) == 0) reds[tid >> 6] = lsum;
    __syncthreads();
    const float inv = 1.0f / (reds[0] + reds[1] + reds[2] + reds[3]);
    for (int s = tid; s < kS; s += 256) attn[b * kS + s] = sc[s] * inv;
}

// ---------------------------------------------------------------------------
// C1: context partials over s-chunks (memory-bound streaming of memory_bank)
__global__ __launch_bounds__(256) void ctx_partial_kernel(
    const float* __restrict__ MBank, const float* __restrict__ attn,
    float* __restrict__ cpart) {
    const int b  = blockIdx.x;   // 64
    const int sc = blockIdx.y;   // 16 chunks of 128 s
    const int m4 = threadIdx.x * 4;
    const float* base = MBank + ((size_t)b * kS + sc * 128) * kM + m4;
    const float* ap = attn + b * kS + sc * 128;
    f32x4 acc = {0.f, 0.f, 0.f, 0.f};
    #pragma unroll 8
    for (int s = 0; s < 128; ++s) {
        const float a = ap[s];
        f32x4 v = *(const f32x4*)(base + (size_t)s * kM);
        acc[0] += a * v[0]; acc[1] += a * v[1];
        acc[2] += a * v[2]; acc[3] += a * v[3];
    }
    *(f32x4*)&cpart[((size_t)(b * 16 + sc)) * kM + m4] = acc;
}

// C2: reduce the 16 s-chunk partials -> context
__global__ __launch_bounds__(256) void ctx_reduce_kernel(
    const float* __restrict__ cpart, float* __restrict__ out) {
    const int idx = blockIdx.x * 256 + threadIdx.x;  // 65536
    const int b = idx >> 10, m = idx & 1023;
    float v = 0.f;
    #pragma unroll
    for (int c = 0; c < 16; ++c) v += cpart[(size_t)((b * 16 + c) << 10) + m];
    out[idx] = v;
}

// ---------------------------------------------------------------------------
extern "C" void kernel_launch(void* const* d_in, const int* in_sizes, int n_in,
                              void* d_out, int out_size, void* d_ws, size_t ws_size,
                              hipStream_t stream) {
    const float* dec   = (const float*)d_in[0];   // [64,1024]
    const float* MBank = (const float*)d_in[1];   // [64,2048,1024]
    const int*   mask  = (const int*)d_in[2];     // [64,2048]
    const float* Wv    = (const float*)d_in[3];   // [1024]
    const float* Wdec  = (const float*)d_in[4];   // [1024,1024]
    const float* Wmem  = (const float*)d_in[5];   // [1024,1024]

    float* out_ctx  = (float*)d_out;              // 65536 floats
    float* out_attn = (float*)d_out + kB * kD;    // 131072 floats

    char* ws = (char*)d_ws;
    bf16*  WT     = (bf16*)ws;                                  // 2 MB
    float* decf   = (float*)(ws + (1 << 21));                   // 256 KB
    float* scores = (float*)(ws + (1 << 21) + (1 << 18));       // 512 KB
    float* cpart  = (float*)(ws + (1 << 21) + (1 << 18) + (1 << 19)); // 4 MB

    wmem_transpose_kernel<<<dim3(16, 16), 256, 0, stream>>>(Wmem, WT);
    dec_project_kernel<<<dim3(64, 16), 256, 0, stream>>>(dec, Wdec, decf);
    attn_scores_kernel<<<2048, 256, 0, stream>>>(MBank, WT, decf, Wv, scores);
    softmax_kernel<<<64, 256, 0, stream>>>(scores, mask, out_attn);
    ctx_partial_kernel<<<dim3(64, 16), 256, 0, stream>>>(MBank, out_attn, cpart);
    ctx_reduce_kernel<<<256, 256, 0, stream>>>(cpart, out_ctx);
}